// Round 11
// baseline (142.176 us; speedup 1.0000x reference)
//
#include <hip/hip_runtime.h>
#include <math.h>

#define CEXP 2.8853900817779268f  // 2*log2(e): tanh(z) = 1 - 2/(2^(c*z)+1)
#define TABN 2048   // s(theta) table cells
#define NC   320    // w(x) grid cells per axis
#define NN   321    // w(x) grid nodes per axis
#define WBLK ((NN * NN + 255) / 256)   // 403 blocks for the w-grid

// Tables (rewritten by prep_kernel on every launch; kernel boundary makes
// them visible to interior_kernel across XCDs).
__device__ float  g_wtab[NN * NN * 8];  // [iy][ix][8] = w-MLP outputs, 3.3 MB
__device__ float2 g_stab2[TABN];        // cell i: {s(p_i), s(p_{i+1}) - s(p_i)}

// tanh with the 2*log2(e) factor pre-folded into the incoming accumulator.
static __device__ __forceinline__ float tanh_pre(float z) {
    float e = __builtin_amdgcn_exp2f(z);
    float r = __builtin_amdgcn_rcpf(e + 1.0f);
    return fmaf(-2.0f, r, 1.0f);
}

// phi-branch s(theta(p)) with LDS-staged, CEXP-prefolded weights, unrolled.
// (Round 10's s_of_p read weights from GLOBAL inside non-unrolled loops on
// only 8 CUs -> ~120k-cycle latency chain = the entire 54 us prep floor.)
static __device__ __forceinline__ float s_of_p_lds(float pth,
    const float* __restrict__ W1, const float* __restrict__ b1,
    const float* __restrict__ W2, const float* __restrict__ b2,
    const float* __restrict__ W3, const float* __restrict__ b3,
    const float* __restrict__ W4, const float* __restrict__ b4)
{
    float th;
    if (pth >= -1.0f && pth <= 1.0f) {
        th = atanf(pth / (1.0f - fabsf(pth)));      // /0 -> inf -> atan=pi/2 ok
    } else if (pth > 1.0f) {
        const float uu = 2.0f - pth;                // [0,1)
        th = (float)M_PI - atanf(uu / (1.0f - uu));
    } else {
        const float uu = -2.0f - pth;               // (-1,0]
        th = -(float)M_PI + atanf(-uu / (1.0f + uu));
    }
    const float cth = cosf(th), sth = sinf(th);

    float h[15], h2[15];
    #pragma unroll
    for (int j = 0; j < 15; ++j)
        h[j] = tanh_pre(fmaf(sth, W1[15 + j], fmaf(cth, W1[j], b1[j])));

    #pragma unroll
    for (int j = 0; j < 15; ++j) h2[j] = b2[j];
    #pragma unroll
    for (int k = 0; k < 15; ++k) {
        const float hk = h[k];
        #pragma unroll
        for (int j = 0; j < 15; ++j) h2[j] = fmaf(hk, W2[k * 15 + j], h2[j]);
    }
    #pragma unroll
    for (int j = 0; j < 15; ++j) h2[j] = tanh_pre(h2[j]);

    #pragma unroll
    for (int j = 0; j < 15; ++j) h[j] = b3[j];
    #pragma unroll
    for (int k = 0; k < 15; ++k) {
        const float hk = h2[k];
        #pragma unroll
        for (int j = 0; j < 15; ++j) h[j] = fmaf(hk, W3[k * 15 + j], h[j]);
    }
    #pragma unroll
    for (int j = 0; j < 15; ++j) h[j] = tanh_pre(h[j]);

    float ph[4];
    #pragma unroll
    for (int j = 0; j < 4; ++j) ph[j] = b4[j];
    #pragma unroll
    for (int k = 0; k < 15; ++k) {
        const float hk = h[k];
        #pragma unroll
        for (int j = 0; j < 4; ++j) ph[j] = fmaf(hk, W4[k * 4 + j], ph[j]);
    }
    return fmaf(ph[1], sinf(0.5f * th),
           fmaf(ph[2], sth,
           fmaf(ph[3], sinf(1.5f * th), ph[0])));
}

// Blocks [0, WBLK): w(x)-grid nodes (LDS-staged weights, unrolled).
// Blocks [WBLK, ...): s(theta) table (LDS-staged phi weights, unrolled).
// Branch is BLOCK-uniform.
__global__ __launch_bounds__(256) void prep_kernel(
    const float* __restrict__ Ww1, const float* __restrict__ bw1,
    const float* __restrict__ Ww2, const float* __restrict__ bw2,
    const float* __restrict__ Ww3, const float* __restrict__ bw3,
    const float* __restrict__ Ww4, const float* __restrict__ bw4,
    const float* __restrict__ Wp1, const float* __restrict__ bp1,
    const float* __restrict__ Wp2, const float* __restrict__ bp2,
    const float* __restrict__ Wp3, const float* __restrict__ bp3,
    const float* __restrict__ Wp4, const float* __restrict__ bp4)
{
    const int t = threadIdx.x;

    if (blockIdx.x < WBLK) {
        // ---- stage prescaled w-weights into LDS ----
        __shared__ float sW1[60], sb1[30], sW2[900], sb2[30],
                         sW3[900], sb3[30], sW4[240], sb4[8];
        for (int i = t; i < 900; i += 256) {
            sW2[i] = CEXP * Ww2[i];
            sW3[i] = CEXP * Ww3[i];
        }
        if (t < 240) sW4[t] = Ww4[t];
        if (t < 60) sW1[t] = CEXP * Ww1[t];
        if (t < 30) {
            sb1[t] = CEXP * bw1[t];
            sb2[t] = CEXP * bw2[t];
            sb3[t] = CEXP * bw3[t];
        }
        if (t < 8) sb4[t] = bw4[t];
        __syncthreads();

        const int gid = blockIdx.x * 256 + t;
        if (gid >= NN * NN) return;
        const int ix = gid % NN, iy = gid / NN;
        const float x0 = (float)ix * (1.0f / (float)NC);
        const float x1 = (float)iy * (1.0f / (float)NC);

        float h[30], a[30];
        #pragma unroll
        for (int j = 0; j < 30; ++j)
            h[j] = tanh_pre(fmaf(x1, sW1[30 + j], fmaf(x0, sW1[j], sb1[j])));

        // layer 2: 30 -> 30 (j-inner, float2 LDS reads)
        #pragma unroll
        for (int j = 0; j < 30; ++j) a[j] = sb2[j];
        #pragma unroll
        for (int k = 0; k < 30; ++k) {
            const float hk = h[k];
            #pragma unroll
            for (int jj = 0; jj < 15; ++jj) {
                const float2 w = *(const float2*)&sW2[k * 30 + 2 * jj];
                a[2 * jj]     = fmaf(hk, w.x, a[2 * jj]);
                a[2 * jj + 1] = fmaf(hk, w.y, a[2 * jj + 1]);
            }
        }
        #pragma unroll
        for (int j = 0; j < 30; ++j) a[j] = tanh_pre(a[j]);

        // layer 3: 30 -> 30
        #pragma unroll
        for (int j = 0; j < 30; ++j) h[j] = sb3[j];
        #pragma unroll
        for (int k = 0; k < 30; ++k) {
            const float ak = a[k];
            #pragma unroll
            for (int jj = 0; jj < 15; ++jj) {
                const float2 w = *(const float2*)&sW3[k * 30 + 2 * jj];
                h[2 * jj]     = fmaf(ak, w.x, h[2 * jj]);
                h[2 * jj + 1] = fmaf(ak, w.y, h[2 * jj + 1]);
            }
        }
        #pragma unroll
        for (int j = 0; j < 30; ++j) h[j] = tanh_pre(h[j]);

        // layer 4: 30 -> 8 (unscaled)
        float o[8];
        #pragma unroll
        for (int j = 0; j < 8; ++j) o[j] = sb4[j];
        #pragma unroll
        for (int k = 0; k < 30; ++k) {
            const float hk = h[k];
            #pragma unroll
            for (int jj = 0; jj < 4; ++jj) {
                const float2 w = *(const float2*)&sW4[k * 8 + 2 * jj];
                o[2 * jj]     = fmaf(hk, w.x, o[2 * jj]);
                o[2 * jj + 1] = fmaf(hk, w.y, o[2 * jj + 1]);
            }
        }
        float4* dst = (float4*)&g_wtab[gid * 8];
        float4 v0; v0.x = o[0]; v0.y = o[1]; v0.z = o[2]; v0.w = o[3];
        float4 v1; v1.x = o[4]; v1.y = o[5]; v1.z = o[6]; v1.w = o[7];
        dst[0] = v0; dst[1] = v1;
        return;
    }

    // ---- s(theta) table blocks: LDS-staged prefolded phi weights ----
    __shared__ float pW1[30], pb1[15], pW2[225], pb2[15],
                     pW3[225], pb3[15], pW4[60], pb4[4];
    if (t < 225) {
        pW2[t] = CEXP * Wp2[t];
        pW3[t] = CEXP * Wp3[t];
    }
    if (t < 60) pW4[t] = Wp4[t];
    if (t < 30) pW1[t] = CEXP * Wp1[t];
    if (t < 15) {
        pb1[t] = CEXP * bp1[t];
        pb2[t] = CEXP * bp2[t];
        pb3[t] = CEXP * bp3[t];
    }
    if (t < 4) pb4[t] = bp4[t];
    __syncthreads();

    const int cell = (blockIdx.x - WBLK) * 256 + t;
    if (cell < TABN) {
        const float hh = 4.0f / (float)TABN;
        const float p0 = -2.0f + hh * (float)cell;
        const float s0 = s_of_p_lds(p0,      pW1, pb1, pW2, pb2, pW3, pb3, pW4, pb4);
        const float s1 = s_of_p_lds(p0 + hh, pW1, pb1, pW2, pb2, pW3, pb3, pW4, pb4);
        float2 e; e.x = s0; e.y = s1 - s0;
        g_stab2[cell] = e;
    }
}

// 2 points per thread. Entire per-point compute is table gathers + ~90 VALU
// ops: bilinear w(x) from the 2-D grid (L2-resident), s(theta) from the 1-D
// table, plus the closed-form geometry/singular-function epilogue.
__global__ __launch_bounds__(256) void interior_kernel(
    const float4* __restrict__ x,      // two points per float4
    const float*  __restrict__ imv,
    const float*  __restrict__ lmbd,
    float* __restrict__ out, int n2)   // n2 = n/2
{
    const int idx = blockIdx.x * blockDim.x + threadIdx.x;
    if (idx >= n2) return;

    const float4 xx = x[idx];
    const float X0[2] = {xx.x, xx.z};
    const float X1[2] = {xx.y, xx.w};
    const float im0 = imv[0], im1 = imv[1], lam = lmbd[0];

    const float4* __restrict__ T = (const float4*)g_wtab;

    float res[2];
    #pragma unroll
    for (int p = 0; p < 2; ++p) {
        const float x0 = X0[p], x1 = X1[p];

        // ---- bilinear gather of w[0..8) from the 2-D grid ----
        const float fx = x0 * (float)NC;
        const float fy = x1 * (float)NC;
        int ix = (int)fx; ix = ix < 0 ? 0 : (ix > NC - 1 ? NC - 1 : ix);
        int iy = (int)fy; iy = iy < 0 ? 0 : (iy > NC - 1 ? NC - 1 : iy);
        const float frx = fx - (float)ix;
        const float fry = fy - (float)iy;

        const int k = (iy * NN + ix) * 2;        // float4 units
        const float4 a0 = T[k],              a1 = T[k + 1];            // (ix  ,iy)
        const float4 b0 = T[k + 2],          b1 = T[k + 3];            // (ix+1,iy)
        const float4 c0 = T[k + NN * 2],     c1 = T[k + NN * 2 + 1];   // (ix  ,iy+1)
        const float4 d0 = T[k + NN * 2 + 2], d1 = T[k + NN * 2 + 3];

        float wv[8];
        {
            const float A[8] = {a0.x, a0.y, a0.z, a0.w, a1.x, a1.y, a1.z, a1.w};
            const float B[8] = {b0.x, b0.y, b0.z, b0.w, b1.x, b1.y, b1.z, b1.w};
            const float C[8] = {c0.x, c0.y, c0.z, c0.w, c1.x, c1.y, c1.z, c1.w};
            const float D[8] = {d0.x, d0.y, d0.z, d0.w, d1.x, d1.y, d1.z, d1.w};
            #pragma unroll
            for (int j = 0; j < 8; ++j) {
                const float r0 = fmaf(frx, B[j] - A[j], A[j]);
                const float r1 = fmaf(frx, D[j] - C[j], C[j]);
                wv[j] = fmaf(fry, r1 - r0, r0);
            }
        }

        // ---- geometry about the interior vertex ----
        const float dx = x0 - im0, dy = x1 - im1;
        const float r  = sqrtf(fmaf(dx, dx, dy * dy));

        // yita(r)
        const float t  = fminf(fmaxf(fmaf(2.5f, r, -1.25f), 0.0f), 1.0f);
        const float t3 = t * t * t;
        const float yv = fmaf(fmaf(fmaf(-6.0f, t, 15.0f), t, -10.0f), t3, 1.0f);

        // r^lambda (sqrt fast path for lambda == 0.5)
        float rl;
        if (lam == 0.5f) rl = sqrtf(r);
        else rl = __builtin_amdgcn_exp2f(lam * __builtin_amdgcn_logf(fmaxf(r, 1e-20f)));

        // diamond-angle parameter p(theta) in [-2,2], no trig
        const float l1n = fmaxf(fabsf(dx) + fabsf(dy), 1e-20f);
        const float u   = dy * __builtin_amdgcn_rcpf(l1n);
        const float pbk = (dy >= 0.0f) ? (2.0f - u) : (-2.0f - u);
        const float pth = (dx >= 0.0f) ? u : pbk;

        // s(theta) table gather: cell {s, ds}, one 8 B load
        const float fi = fminf(fmaxf(fmaf(pth, (float)(TABN / 4), (float)(TABN / 2)),
                                     0.0f), (float)TABN - 0.001f);
        const int   ii = (int)fi;
        const float fr = fi - (float)ii;
        const float2 sd = g_stab2[ii];
        const float sval = fmaf(fr, sd.y, sd.x);

        // singular functions at x (about origin), algebraically reduced:
        // vp0 = r0^0.5 sin(th/2) = copysign(sqrt((r0-x0)/2), x1)
        // vp1 = x1
        // vp2 = r0^1.5 sin(1.5 th) = x1*sqrt((r0+x0)/2) + x0*vp0
        const float r0 = sqrtf(fmaf(x0, x0, x1 * x1));
        const float A  = sqrtf(fmaxf(0.0f, (r0 - x0) * 0.5f));
        const float Bq = sqrtf(fmaxf(0.0f, (r0 + x0) * 0.5f));
        const float vp0 = copysignf(A, x1);
        const float vp2 = fmaf(x1, Bq, x0 * vp0);

        // combine
        float rp = fmaf(yv, wv[4], wv[0]);
        rp = fmaf(fmaf(wv[5], yv, wv[1]), vp0, rp);
        rp = fmaf(fmaf(wv[6], yv, wv[2]), x1, rp);
        rp = fmaf(fmaf(wv[7], yv, wv[3]), vp2, rp);
        res[p] = fmaf(sval * yv, rl, rp);
    }

    float2 o; o.x = res[0]; o.y = res[1];
    ((float2*)out)[idx] = o;
}

extern "C" void kernel_launch(void* const* d_in, const int* in_sizes, int n_in,
                              void* d_out, int out_size, void* d_ws, size_t ws_size,
                              hipStream_t stream) {
    const float4* x   = (const float4*)d_in[0];
    const float* imv  = (const float*)d_in[1];
    const float* lmbd = (const float*)d_in[2];
    const float* Ww1  = (const float*)d_in[3];
    const float* bw1  = (const float*)d_in[4];
    const float* Ww2  = (const float*)d_in[5];
    const float* bw2  = (const float*)d_in[6];
    const float* Ww3  = (const float*)d_in[7];
    const float* bw3  = (const float*)d_in[8];
    const float* Ww4  = (const float*)d_in[9];
    const float* bw4  = (const float*)d_in[10];
    const float* Wp1  = (const float*)d_in[11];
    const float* bp1  = (const float*)d_in[12];
    const float* Wp2  = (const float*)d_in[13];
    const float* bp2  = (const float*)d_in[14];
    const float* Wp3  = (const float*)d_in[15];
    const float* bp3  = (const float*)d_in[16];
    const float* Wp4  = (const float*)d_in[17];
    const float* bp4  = (const float*)d_in[18];
    float* out = (float*)d_out;

    const int n  = in_sizes[0] / 2;
    const int n2 = n / 2;

    // WBLK blocks for the w-grid + 8 blocks for the s-table.
    prep_kernel<<<WBLK + (TABN + 255) / 256, 256, 0, stream>>>(
        Ww1, bw1, Ww2, bw2, Ww3, bw3, Ww4, bw4,
        Wp1, bp1, Wp2, bp2, Wp3, bp3, Wp4, bp4);

    const int block = 256;
    const int grid = (n2 + block - 1) / block;
    interior_kernel<<<grid, block, 0, stream>>>(x, imv, lmbd, out, n2);
}